// Round 1
// 709.329 us; speedup vs baseline: 1.3416x; 1.3416x over previous
//
#include <hip/hip_runtime.h>
#include <cstdint>

typedef __attribute__((ext_vector_type(8))) short short8;
typedef __attribute__((ext_vector_type(4))) float v4f;

#define B_ 4
#define C_ 128
#define K_ 64
#define H_ 256
#define W_ 256
#define HW_ (H_*W_)
#define L_ 1024
#define J_ 256
#define LC 128
#define NCH 8

// ws byte offsets
#define OFF_WFH  0ull
#define OFF_WFL  131072ull
#define OFF_WOF  262144ull
#define OFF_BIAS 327680ull
#define OFF_VWS  335872ull
#define OFF_MFR  (OFF_VWS + 33554432ull)

static __device__ __forceinline__ unsigned short f2bf(float x) {
    unsigned u = __builtin_bit_cast(unsigned, x);
    unsigned r = (u + 0x7FFFu + ((u >> 16) & 1u)) >> 16;
    return (unsigned short)r;
}
static __device__ __forceinline__ float bf2f(unsigned short h) {
    unsigned u = ((unsigned)h) << 16;
    return __builtin_bit_cast(float, u);
}
static __device__ __forceinline__ v4f mfma16(short8 a, short8 b, v4f c) {
    return __builtin_amdgcn_mfma_f32_16x16x32_bf16(a, b, c, 0, 0, 0);
}

union U8 { unsigned short u[8]; short8 v; };

// ---------------- prep: pack weights into MFMA A-fragment order ----------------
__global__ void prep_kernel(const float* __restrict__ w_v, const float* __restrict__ b_v,
                            const float* __restrict__ w1_1, const float* __restrict__ b1_1,
                            const float* __restrict__ w2_1, const float* __restrict__ b2_1,
                            const float* __restrict__ wout1,
                            const float* __restrict__ w1_2, const float* __restrict__ b1_2,
                            const float* __restrict__ w2_2, const float* __restrict__ b2_2,
                            const float* __restrict__ wout2,
                            char* __restrict__ wsb) {
    int tid = blockIdx.x * 256 + threadIdx.x;
    if (tid < 65536) {
        // proj weights: [s][omt 16][kc 4][lane 64][jj 8], rows o: w1(128), w2(64), wv-half(64)
        int jj = tid & 7, lane = (tid >> 3) & 63, kc = (tid >> 9) & 3;
        int omt = (tid >> 11) & 15, s = (tid >> 15) & 1;
        int o = omt * 16 + (lane & 15);
        int c = kc * 32 + ((lane >> 4) * 8) + jj;
        const float* w1 = s ? w1_2 : w1_1;
        const float* w2 = s ? w2_2 : w2_1;
        float v;
        if (o < 128)      v = w1[o * 128 + c];
        else if (o < 192) v = w2[(o - 128) * 128 + c];
        else              v = w_v[(o - 192) * 256 + s * 128 + c];
        unsigned short hi = f2bf(v);
        unsigned short lo = f2bf(v - bf2f(hi));
        ((unsigned short*)(wsb + OFF_WFH))[tid] = hi;
        ((unsigned short*)(wsb + OFF_WFL))[tid] = lo;
    } else if (tid < 98304) {
        int id = tid - 65536;
        int jj = id & 7, lane = (id >> 3) & 63, kc = (id >> 9) & 3;
        int om = (id >> 11) & 7, s = (id >> 14) & 1;
        int o = om * 16 + (lane & 15);
        int c = kc * 32 + ((lane >> 4) * 8) + jj;
        const float* wo = s ? wout2 : wout1;
        ((unsigned short*)(wsb + OFF_WOF))[id] = f2bf(wo[o * 128 + c]);
    } else if (tid < 98816) {
        int id = tid - 98304;
        int s = id >> 8, o = id & 255;
        const float* b1 = s ? b1_2 : b1_1;
        const float* b2 = s ? b2_2 : b2_1;
        float v;
        if (o < 128)      v = b1[o];
        else if (o < 192) v = b2[o - 128];
        else              v = b_v[o - 192];
        ((float*)(wsb + OFF_BIAS))[id] = v;
    }
}

// ---------------- fused per-j kernel ----------------
// waves 0-3: Y1 rows (c 0..127); waves 4-5: Y2 rows (k 0..63); waves 6-7: V logits
__global__ __attribute__((amdgpu_flat_work_group_size(512, 512), amdgpu_waves_per_eu(2, 2)))
void fused_kernel(
    const float* __restrict__ x1, const float* __restrict__ x2,
    char* __restrict__ wsb) {
    // LDS layout (reused regions for epilogue)
    __shared__ __align__(16) char smem[151040];
    unsigned short* Xfh = (unsigned short*)&smem[0];       // B-frag order [ln8][kc4][lane][8]
    unsigned short* Xfl = (unsigned short*)&smem[32768];
    unsigned short* Y1b = (unsigned short*)&smem[65536];   // [128 c][136 l] bf16
    unsigned short* Y2b = (unsigned short*)&smem[100352];  // [64 k][136 l] bf16
    float*          LG  = (float*)&smem[117760];           // [128 l][65 k] fp32
    float*          UF  = (float*)&smem[0];                // [64 k][133 c] fp32 (epilogue)
    unsigned short* UH  = (unsigned short*)&smem[100352];  // [64 k][136 c] bf16 (epilogue)
    unsigned short* MB  = (unsigned short*)&smem[65536];   // [128 o][72 k] bf16 (epilogue)

    const unsigned short* wfh = (const unsigned short*)(wsb + OFF_WFH);
    const unsigned short* wfl = (const unsigned short*)(wsb + OFF_WFL);
    const unsigned short* wof = (const unsigned short*)(wsb + OFF_WOF);
    const float* biasws = (const float*)(wsb + OFF_BIAS);
    unsigned short* vws = (unsigned short*)(wsb + OFF_VWS);
    unsigned short* mfr = (unsigned short*)(wsb + OFF_MFR);

    const int t = threadIdx.x;
    const int lane = t & 63;
    const int w = __builtin_amdgcn_readfirstlane(t >> 6);
    const int j = blockIdx.x;
    const int b = j >> 6, q = j & 63, i0 = q >> 3, i2 = q & 7;
    const long imgbase = (long)b * C_ * HW_ + (long)(i0 * 32) * W_ + i2 * 32;

    const int lquad = lane >> 4;        // 0..3
    const int lmod = lane & 15;

    // biases per lane (rows o = w*32 + h*16 + lquad*4 + r)
    float pb[2][2][4];
#pragma unroll
    for (int s = 0; s < 2; s++)
#pragma unroll
        for (int h = 0; h < 2; h++)
#pragma unroll
            for (int r = 0; r < 4; r++)
                pb[s][h][r] = biasws[s * 256 + w * 32 + h * 16 + lquad * 4 + r];

    v4f uacc[2][4];
#pragma unroll
    for (int s = 0; s < 2; s++)
#pragma unroll
        for (int kn = 0; kn < 4; kn++)
            uacc[s][kn] = (v4f){0.f, 0.f, 0.f, 0.f};

    // staging decode
    const int dl = t & 127, c8 = t >> 7;
    const int srow = dl >> 5, scol = dl & 31;
    const int sln = dl >> 4, slp = dl & 15;

    // prefetch first chunk (lc=0, s=0) into registers
    float R[32];
#pragma unroll
    for (int p = 0; p < 4; p++)
#pragma unroll
        for (int jj = 0; jj < 8; jj++) {
            int c = (p * 4 + c8) * 8 + jj;
            R[p * 8 + jj] = x1[imgbase + (long)c * HW_ + srow * W_ + scol];
        }

    for (int lc = 0; lc < NCH; lc++) {
        v4f pacc[2][8];
#pragma unroll
        for (int s = 0; s < 2; s++) {
            // ---- convert prefetched R (fp32 -> bf16 hi/lo, B-frag order) into LDS ----
#pragma unroll
            for (int p = 0; p < 4; p++) {
                U8 hv, lv;
#pragma unroll
                for (int jj = 0; jj < 8; jj++) {
                    float v = R[p * 8 + jj];
                    unsigned short hh = f2bf(v);
                    hv.u[jj] = hh;
                    lv.u[jj] = f2bf(v - bf2f(hh));
                }
                int co = p * 4 + c8;
                int base = ((sln * 4 + (co >> 2)) * 64 + ((co & 3) * 16 + slp)) * 8;
                *(short8*)&Xfh[base] = hv.v;
                *(short8*)&Xfl[base] = lv.v;
            }
            __syncthreads();
            // ---- issue next-stage x loads; they ride under the MFMA phase ----
            if (s == 0 || lc < NCH - 1) {
                const float* xp = s ? x1 : x2;       // (lc,0)->(lc,1) reads x2; (lc,1)->(lc+1,0) reads x1
                const int nlc = s ? lc + 1 : lc;
#pragma unroll
                for (int p = 0; p < 4; p++)
#pragma unroll
                    for (int jj = 0; jj < 8; jj++) {
                        int c = (p * 4 + c8) * 8 + jj;
                        R[p * 8 + jj] = xp[imgbase + (long)c * HW_ + (nlc * 4 + srow) * W_ + scol];
                    }
            }
            // ---- projection MFMAs (split-3: Whi*Xhi + Wlo*Xhi + Whi*Xlo) ----
            if (s == 0 || w < 6) {
#pragma unroll
                for (int h = 0; h < 2; h++)
#pragma unroll
                    for (int ln = 0; ln < 8; ln++)
                        pacc[h][ln] = (v4f){pb[s][h][0], pb[s][h][1], pb[s][h][2], pb[s][h][3]};
            }
#pragma unroll
            for (int kc = 0; kc < 4; kc++) {
                int wi0 = (((s * 16 + (w * 2 + 0)) * 4 + kc) * 64 + lane) * 8;
                int wi1 = (((s * 16 + (w * 2 + 1)) * 4 + kc) * 64 + lane) * 8;
                short8 wh0 = *(const short8*)&wfh[wi0];
                short8 wh1 = *(const short8*)&wfh[wi1];
                short8 wlo0 = *(const short8*)&wfl[wi0];
                short8 wlo1 = *(const short8*)&wfl[wi1];
#pragma unroll
                for (int ln = 0; ln < 8; ln++) {
                    short8 bh = *(const short8*)&Xfh[((ln * 4 + kc) * 64 + lane) * 8];
                    short8 bl = *(const short8*)&Xfl[((ln * 4 + kc) * 64 + lane) * 8];
                    pacc[0][ln] = mfma16(wh0, bh, pacc[0][ln]);
                    pacc[0][ln] = mfma16(wlo0, bh, pacc[0][ln]);
                    pacc[0][ln] = mfma16(wh0, bl, pacc[0][ln]);
                    pacc[1][ln] = mfma16(wh1, bh, pacc[1][ln]);
                    pacc[1][ln] = mfma16(wlo1, bh, pacc[1][ln]);
                    pacc[1][ln] = mfma16(wh1, bl, pacc[1][ln]);
                }
            }
            // ---- write Y / logits ----
            if (w < 4) {
#pragma unroll
                for (int h = 0; h < 2; h++)
#pragma unroll
                    for (int ln = 0; ln < 8; ln++)
#pragma unroll
                        for (int r = 0; r < 4; r++)
                            Y1b[(w * 32 + h * 16 + lquad * 4 + r) * 136 + ln * 16 + lmod] = f2bf(pacc[h][ln][r]);
            } else if (w < 6) {
#pragma unroll
                for (int h = 0; h < 2; h++)
#pragma unroll
                    for (int ln = 0; ln < 8; ln++)
#pragma unroll
                        for (int r = 0; r < 4; r++)
                            Y2b[((w - 4) * 32 + h * 16 + lquad * 4 + r) * 136 + ln * 16 + lmod] = f2bf(pacc[h][ln][r]);
            } else if (s == 1) {
#pragma unroll
                for (int h = 0; h < 2; h++)
#pragma unroll
                    for (int ln = 0; ln < 8; ln++)
#pragma unroll
                        for (int r = 0; r < 4; r++)
                            LG[(ln * 16 + lmod) * 65 + (w - 6) * 32 + h * 16 + lquad * 4 + r] = pacc[h][ln][r];
            }
            __syncthreads();
            // ---- U-MFMA: U_s += Y1 @ Y2^T over this l-chunk ----
#pragma unroll
            for (int kcl = 0; kcl < 4; kcl++) {
                short8 a = *(const short8*)&Y1b[(w * 16 + lmod) * 136 + kcl * 32 + lquad * 8];
#pragma unroll
                for (int kn = 0; kn < 4; kn++) {
                    short8 bb = *(const short8*)&Y2b[(kn * 16 + lmod) * 136 + kcl * 32 + lquad * 8];
                    uacc[s][kn] = mfma16(a, bb, uacc[s][kn]);
                }
            }
            if (s == 1) {
                // ---- softmax over k per column l ----
                if (t < 128) {
                    float* row = &LG[t * 65];
                    float mx = row[0];
#pragma unroll 8
                    for (int k = 1; k < 64; k++) mx = fmaxf(mx, row[k]);
                    float ssum = 0.f;
#pragma unroll 8
                    for (int k = 0; k < 64; k++) { float e = __expf(row[k] - mx); row[k] = e; ssum += e; }
                    float rs = 1.f / ssum;
#pragma unroll 8
                    for (int k = 0; k < 64; k++) row[k] *= rs;
                }
                __syncthreads();
                // ---- V store (bf16, [j][l][k]) ----
                {
                    int l2 = t >> 2, kq = (t & 3) * 16;
                    U8 o1, o2;
#pragma unroll
                    for (int i = 0; i < 8; i++) o1.u[i] = f2bf(LG[l2 * 65 + kq + i]);
#pragma unroll
                    for (int i = 0; i < 8; i++) o2.u[i] = f2bf(LG[l2 * 65 + kq + 8 + i]);
                    unsigned long long vb = ((unsigned long long)j * 1024 + lc * 128 + l2) * 64 + kq;
                    *(short8*)&vws[vb] = o1.v;
                    *(short8*)&vws[vb + 8] = o2.v;
                }
            }
        }
    }

    // ---------------- epilogue: l2norm(U) -> M = Wout @ Un -> mfrag ----------------
#pragma unroll
    for (int s = 0; s < 2; s++) {
        __syncthreads();
#pragma unroll
        for (int kn = 0; kn < 4; kn++)
#pragma unroll
            for (int r = 0; r < 4; r++)
                UF[(kn * 16 + lmod) * 133 + w * 16 + lquad * 4 + r] = uacc[s][kn][r];
        __syncthreads();
        if (t < 64) {
            const float* rp = &UF[t * 133];
            float ss = 0.f;
#pragma unroll 8
            for (int c = 0; c < 128; c++) ss += rp[c] * rp[c];
            UF[t * 133 + 128] = 1.f / (1e-6f + sqrtf(ss));
        }
        __syncthreads();
        {
            int kk = t >> 3, c0 = (t & 7) * 16;
            float rn = UF[kk * 133 + 128];
#pragma unroll
            for (int i = 0; i < 16; i++)
                UH[kk * 136 + c0 + i] = f2bf(UF[kk * 133 + c0 + i] * rn);
        }
        __syncthreads();
        v4f macc[4];
#pragma unroll
        for (int kn = 0; kn < 4; kn++) macc[kn] = (v4f){0.f, 0.f, 0.f, 0.f};
#pragma unroll
        for (int kc = 0; kc < 4; kc++) {
            short8 a = *(const short8*)&wof[(((s * 8 + w) * 4 + kc) * 64 + lane) * 8];
#pragma unroll
            for (int kn = 0; kn < 4; kn++) {
                short8 bb = *(const short8*)&UH[(kn * 16 + lmod) * 136 + kc * 32 + lquad * 8];
                macc[kn] = mfma16(a, bb, macc[kn]);
            }
        }
        __syncthreads();
#pragma unroll
        for (int kn = 0; kn < 4; kn++)
#pragma unroll
            for (int r = 0; r < 4; r++)
                MB[(w * 16 + lquad * 4 + r) * 72 + kn * 16 + lmod] = f2bf(macc[kn][r]);
        __syncthreads();
#pragma unroll
        for (int p = 0; p < 2; p++) {
            int id = p * 512 + t;
            int om = id >> 7, kc = (id >> 6) & 1, l2 = id & 63;
            short8 mv = *(const short8*)&MB[(om * 16 + (l2 & 15)) * 72 + kc * 32 + ((l2 >> 4) * 8)];
            *(short8*)&mfr[(((unsigned long long)j * 2 + s) * 1024 + id) * 8] = mv;
        }
    }
}

// ---------------- out = M @ V, scattered to image layout ----------------
// Operand-swapped MFMA (A=V, B=M): acc[r] spans 4 consecutive l (w-dim) ->
// one dwordx4 store per (s, ln) instead of 4 scalar stores.
// Grid: 1024 = 256 j x 4 l-slices (16 ln-groups each) for >=2 blocks/CU.
__global__ __launch_bounds__(512, 4) void out_kernel(const char* __restrict__ wsb,
                                                     float* __restrict__ out) {
    const unsigned short* vws = (const unsigned short*)(wsb + OFF_VWS);
    const unsigned short* mfr = (const unsigned short*)(wsb + OFF_MFR);
    const int t = threadIdx.x;
    const int lane = t & 63;
    const int w = __builtin_amdgcn_readfirstlane(t >> 6);
    const int j = blockIdx.x >> 2;
    const int slice = blockIdx.x & 3;
    const int b = j >> 6, q = j & 63, i0 = q >> 3, i2 = q & 7;
    const long obase = (long)b * C_ * HW_ + (long)(i0 * 32) * W_ + i2 * 32;
    const int lquad = lane >> 4, lmod = lane & 15;

    short8 afr[2][2];
#pragma unroll
    for (int s = 0; s < 2; s++)
#pragma unroll
        for (int kc = 0; kc < 2; kc++)
            afr[s][kc] = *(const short8*)&mfr[(((unsigned long long)j * 2 + s) * 1024 + (w * 2 + kc) * 64 + lane) * 8];

    const long orow = obase + (long)(w * 16 + lmod) * HW_;   // this lane's output channel row
#pragma unroll 4
    for (int i = 0; i < 16; i++) {
        int ln = slice * 16 + i;
        int l = ln * 16 + lmod;                               // V-frag row (A-operand)
        short8 b0  = *(const short8*)&vws[((unsigned long long)j * 1024 + l) * 64 + lquad * 8];
        short8 b1v = *(const short8*)&vws[((unsigned long long)j * 1024 + l) * 64 + 32 + lquad * 8];
        int lo = ln * 16 + lquad * 4;                         // first l of this lane's acc
        long base2 = orow + (long)(lo >> 5) * W_ + (lo & 31);
#pragma unroll
        for (int s = 0; s < 2; s++) {
            v4f acc = {0.f, 0.f, 0.f, 0.f};
            acc = mfma16(b0,  afr[s][0], acc);
            acc = mfma16(b1v, afr[s][1], acc);
            *(v4f*)&out[base2 + (long)s * B_ * C_ * HW_] = acc;
        }
    }
}

extern "C" void kernel_launch(void* const* d_in, const int* in_sizes, int n_in,
                              void* d_out, int out_size, void* d_ws, size_t ws_size,
                              hipStream_t stream) {
    (void)in_sizes; (void)n_in; (void)out_size; (void)ws_size;
    const float* x1    = (const float*)d_in[0];
    const float* x2    = (const float*)d_in[1];
    const float* w_v   = (const float*)d_in[2];
    const float* b_v   = (const float*)d_in[3];
    const float* w1_1  = (const float*)d_in[4];
    const float* b1_1  = (const float*)d_in[5];
    const float* w2_1  = (const float*)d_in[6];
    const float* b2_1  = (const float*)d_in[7];
    const float* wout1 = (const float*)d_in[8];
    const float* w1_2  = (const float*)d_in[9];
    const float* b1_2  = (const float*)d_in[10];
    const float* w2_2  = (const float*)d_in[11];
    const float* b2_2  = (const float*)d_in[12];
    const float* wout2 = (const float*)d_in[13];
    char* wsb  = (char*)d_ws;
    float* out = (float*)d_out;

    hipLaunchKernelGGL(prep_kernel, dim3(386), dim3(256), 0, stream,
                       w_v, b_v, w1_1, b1_1, w2_1, b2_1, wout1,
                       w1_2, b1_2, w2_2, b2_2, wout2, wsb);
    hipLaunchKernelGGL(fused_kernel, dim3(J_), dim3(512), 0, stream, x1, x2, wsb);
    hipLaunchKernelGGL(out_kernel, dim3(J_ * 4), dim3(512), 0, stream, wsb, out);
}

// Round 2
// 682.771 us; speedup vs baseline: 1.3937x; 1.0389x over previous
//
#include <hip/hip_runtime.h>
#include <cstdint>

typedef __attribute__((ext_vector_type(8))) short short8;
typedef __attribute__((ext_vector_type(4))) float v4f;

#define B_ 4
#define C_ 128
#define K_ 64
#define H_ 256
#define W_ 256
#define HW_ (H_*W_)
#define L_ 1024
#define J_ 256
#define LC 128
#define NCH 8

// ws byte offsets
#define OFF_WFH  0ull
#define OFF_WFL  131072ull
#define OFF_WOF  262144ull
#define OFF_BIAS 327680ull
#define OFF_VWS  335872ull

static __device__ __forceinline__ unsigned short f2bf(float x) {
    unsigned u = __builtin_bit_cast(unsigned, x);
    unsigned r = (u + 0x7FFFu + ((u >> 16) & 1u)) >> 16;
    return (unsigned short)r;
}
static __device__ __forceinline__ float bf2f(unsigned short h) {
    unsigned u = ((unsigned)h) << 16;
    return __builtin_bit_cast(float, u);
}
static __device__ __forceinline__ v4f mfma16(short8 a, short8 b, v4f c) {
    return __builtin_amdgcn_mfma_f32_16x16x32_bf16(a, b, c, 0, 0, 0);
}

union U8 { unsigned short u[8]; short8 v; };

// ---------------- prep: pack weights into MFMA A-fragment order ----------------
__global__ void prep_kernel(const float* __restrict__ w_v, const float* __restrict__ b_v,
                            const float* __restrict__ w1_1, const float* __restrict__ b1_1,
                            const float* __restrict__ w2_1, const float* __restrict__ b2_1,
                            const float* __restrict__ wout1,
                            const float* __restrict__ w1_2, const float* __restrict__ b1_2,
                            const float* __restrict__ w2_2, const float* __restrict__ b2_2,
                            const float* __restrict__ wout2,
                            char* __restrict__ wsb) {
    int tid = blockIdx.x * 256 + threadIdx.x;
    if (tid < 65536) {
        // proj weights: [s][omt 16][kc 4][lane 64][jj 8], rows o: w1(128), w2(64), wv-half(64)
        int jj = tid & 7, lane = (tid >> 3) & 63, kc = (tid >> 9) & 3;
        int omt = (tid >> 11) & 15, s = (tid >> 15) & 1;
        int o = omt * 16 + (lane & 15);
        int c = kc * 32 + ((lane >> 4) * 8) + jj;
        const float* w1 = s ? w1_2 : w1_1;
        const float* w2 = s ? w2_2 : w2_1;
        float v;
        if (o < 128)      v = w1[o * 128 + c];
        else if (o < 192) v = w2[(o - 128) * 128 + c];
        else              v = w_v[(o - 192) * 256 + s * 128 + c];
        unsigned short hi = f2bf(v);
        unsigned short lo = f2bf(v - bf2f(hi));
        ((unsigned short*)(wsb + OFF_WFH))[tid] = hi;
        ((unsigned short*)(wsb + OFF_WFL))[tid] = lo;
    } else if (tid < 98304) {
        int id = tid - 65536;
        int jj = id & 7, lane = (id >> 3) & 63, kc = (id >> 9) & 3;
        int om = (id >> 11) & 7, s = (id >> 14) & 1;
        int o = om * 16 + (lane & 15);
        int c = kc * 32 + ((lane >> 4) * 8) + jj;
        const float* wo = s ? wout2 : wout1;
        ((unsigned short*)(wsb + OFF_WOF))[id] = f2bf(wo[o * 128 + c]);
    } else if (tid < 98816) {
        int id = tid - 98304;
        int s = id >> 8, o = id & 255;
        const float* b1 = s ? b1_2 : b1_1;
        const float* b2 = s ? b2_2 : b2_1;
        float v;
        if (o < 128)      v = b1[o];
        else if (o < 192) v = b2[o - 128];
        else              v = b_v[o - 192];
        ((float*)(wsb + OFF_BIAS))[id] = v;
    }
}

// ---------------- fused per-j kernel (proj + U + softmax/V + l2norm + M + out) ----
// waves 0-3: Y1 rows (c 0..127); waves 4-5: Y2 rows (k 0..63); waves 6-7: V logits
__global__ __attribute__((amdgpu_flat_work_group_size(512, 512), amdgpu_waves_per_eu(2, 2)))
void fused_kernel(
    const float* __restrict__ x1, const float* __restrict__ x2,
    char* __restrict__ wsb, float* __restrict__ out) {
    // LDS layout (reused regions for epilogue)
    __shared__ __align__(16) char smem[151040];
    unsigned short* Xfh = (unsigned short*)&smem[0];       // B-frag order [ln8][kc4][lane][8]
    unsigned short* Xfl = (unsigned short*)&smem[32768];
    unsigned short* Y1b = (unsigned short*)&smem[65536];   // [128 c][136 l] bf16
    unsigned short* Y2b = (unsigned short*)&smem[100352];  // [64 k][136 l] bf16
    float*          LG  = (float*)&smem[117760];           // [128 l][65 k] fp32
    float*          UF  = (float*)&smem[0];                // [64 k][133 c] fp32 (epilogue)
    unsigned short* UH  = (unsigned short*)&smem[100352];  // [64 k][136 c] bf16 (epilogue)
    unsigned short* MB  = (unsigned short*)&smem[65536];   // [128 o][72 k] bf16 (epilogue)

    const unsigned short* wfh = (const unsigned short*)(wsb + OFF_WFH);
    const unsigned short* wfl = (const unsigned short*)(wsb + OFF_WFL);
    const unsigned short* wof = (const unsigned short*)(wsb + OFF_WOF);
    const float* biasws = (const float*)(wsb + OFF_BIAS);
    unsigned short* vws = (unsigned short*)(wsb + OFF_VWS);

    const int t = threadIdx.x;
    const int lane = t & 63;
    const int w = __builtin_amdgcn_readfirstlane(t >> 6);
    const int j = blockIdx.x;
    const int b = j >> 6, q = j & 63, i0 = q >> 3, i2 = q & 7;
    const long imgbase = (long)b * C_ * HW_ + (long)(i0 * 32) * W_ + i2 * 32;

    const int lquad = lane >> 4;        // 0..3
    const int lmod = lane & 15;

    // biases per lane (rows o = w*32 + h*16 + lquad*4 + r)
    float pb[2][2][4];
#pragma unroll
    for (int s = 0; s < 2; s++)
#pragma unroll
        for (int h = 0; h < 2; h++)
#pragma unroll
            for (int r = 0; r < 4; r++)
                pb[s][h][r] = biasws[s * 256 + w * 32 + h * 16 + lquad * 4 + r];

    v4f uacc[2][4];
#pragma unroll
    for (int s = 0; s < 2; s++)
#pragma unroll
        for (int kn = 0; kn < 4; kn++)
            uacc[s][kn] = (v4f){0.f, 0.f, 0.f, 0.f};

    // staging decode
    const int dl = t & 127, c8 = t >> 7;
    const int srow = dl >> 5, scol = dl & 31;
    const int sln = dl >> 4, slp = dl & 15;

    // prefetch first chunk (lc=0, s=0) into registers
    float R[32];
#pragma unroll
    for (int p = 0; p < 4; p++)
#pragma unroll
        for (int jj = 0; jj < 8; jj++) {
            int c = (p * 4 + c8) * 8 + jj;
            R[p * 8 + jj] = x1[imgbase + (long)c * HW_ + srow * W_ + scol];
        }

    for (int lc = 0; lc < NCH; lc++) {
        v4f pacc[2][8];
#pragma unroll
        for (int s = 0; s < 2; s++) {
            // ---- convert prefetched R (fp32 -> bf16 hi/lo, B-frag order) into LDS ----
#pragma unroll
            for (int p = 0; p < 4; p++) {
                U8 hv, lv;
#pragma unroll
                for (int jj = 0; jj < 8; jj++) {
                    float v = R[p * 8 + jj];
                    unsigned short hh = f2bf(v);
                    hv.u[jj] = hh;
                    lv.u[jj] = f2bf(v - bf2f(hh));
                }
                int co = p * 4 + c8;
                int base = ((sln * 4 + (co >> 2)) * 64 + ((co & 3) * 16 + slp)) * 8;
                *(short8*)&Xfh[base] = hv.v;
                *(short8*)&Xfl[base] = lv.v;
            }
            __syncthreads();
            // ---- issue next-stage x loads; they ride under the MFMA phase ----
            if (s == 0 || lc < NCH - 1) {
                const float* xp = s ? x1 : x2;       // (lc,0)->(lc,1) reads x2; (lc,1)->(lc+1,0) reads x1
                const int nlc = s ? lc + 1 : lc;
#pragma unroll
                for (int p = 0; p < 4; p++)
#pragma unroll
                    for (int jj = 0; jj < 8; jj++) {
                        int c = (p * 4 + c8) * 8 + jj;
                        R[p * 8 + jj] = xp[imgbase + (long)c * HW_ + (nlc * 4 + srow) * W_ + scol];
                    }
            }
            // ---- projection MFMAs (split-3: Whi*Xhi + Wlo*Xhi + Whi*Xlo) ----
            if (s == 0 || w < 6) {
#pragma unroll
                for (int h = 0; h < 2; h++)
#pragma unroll
                    for (int ln = 0; ln < 8; ln++)
                        pacc[h][ln] = (v4f){pb[s][h][0], pb[s][h][1], pb[s][h][2], pb[s][h][3]};
            }
#pragma unroll
            for (int kc = 0; kc < 4; kc++) {
                int wi0 = (((s * 16 + (w * 2 + 0)) * 4 + kc) * 64 + lane) * 8;
                int wi1 = (((s * 16 + (w * 2 + 1)) * 4 + kc) * 64 + lane) * 8;
                short8 wh0 = *(const short8*)&wfh[wi0];
                short8 wh1 = *(const short8*)&wfh[wi1];
                short8 wlo0 = *(const short8*)&wfl[wi0];
                short8 wlo1 = *(const short8*)&wfl[wi1];
#pragma unroll
                for (int ln = 0; ln < 8; ln++) {
                    short8 bh = *(const short8*)&Xfh[((ln * 4 + kc) * 64 + lane) * 8];
                    short8 bl = *(const short8*)&Xfl[((ln * 4 + kc) * 64 + lane) * 8];
                    pacc[0][ln] = mfma16(wh0, bh, pacc[0][ln]);
                    pacc[0][ln] = mfma16(wlo0, bh, pacc[0][ln]);
                    pacc[0][ln] = mfma16(wh0, bl, pacc[0][ln]);
                    pacc[1][ln] = mfma16(wh1, bh, pacc[1][ln]);
                    pacc[1][ln] = mfma16(wlo1, bh, pacc[1][ln]);
                    pacc[1][ln] = mfma16(wh1, bl, pacc[1][ln]);
                }
            }
            // ---- write Y / logits ----
            if (w < 4) {
#pragma unroll
                for (int h = 0; h < 2; h++)
#pragma unroll
                    for (int ln = 0; ln < 8; ln++)
#pragma unroll
                        for (int r = 0; r < 4; r++)
                            Y1b[(w * 32 + h * 16 + lquad * 4 + r) * 136 + ln * 16 + lmod] = f2bf(pacc[h][ln][r]);
            } else if (w < 6) {
#pragma unroll
                for (int h = 0; h < 2; h++)
#pragma unroll
                    for (int ln = 0; ln < 8; ln++)
#pragma unroll
                        for (int r = 0; r < 4; r++)
                            Y2b[((w - 4) * 32 + h * 16 + lquad * 4 + r) * 136 + ln * 16 + lmod] = f2bf(pacc[h][ln][r]);
            } else if (s == 1) {
#pragma unroll
                for (int h = 0; h < 2; h++)
#pragma unroll
                    for (int ln = 0; ln < 8; ln++)
#pragma unroll
                        for (int r = 0; r < 4; r++)
                            LG[(ln * 16 + lmod) * 65 + (w - 6) * 32 + h * 16 + lquad * 4 + r] = pacc[h][ln][r];
            }
            __syncthreads();
            // ---- U-MFMA: U_s += Y1 @ Y2^T over this l-chunk ----
#pragma unroll
            for (int kcl = 0; kcl < 4; kcl++) {
                short8 a = *(const short8*)&Y1b[(w * 16 + lmod) * 136 + kcl * 32 + lquad * 8];
#pragma unroll
                for (int kn = 0; kn < 4; kn++) {
                    short8 bb = *(const short8*)&Y2b[(kn * 16 + lmod) * 136 + kcl * 32 + lquad * 8];
                    uacc[s][kn] = mfma16(a, bb, uacc[s][kn]);
                }
            }
            if (s == 1) {
                // ---- wave-parallel softmax + direct V store (all 512 threads) ----
                // 4 threads per l-column: thread part=t&3 owns k in [part*16, part*16+16)
                int l2 = t >> 2, part = t & 3;
                float vv[16];
#pragma unroll
                for (int i = 0; i < 16; i++) vv[i] = LG[l2 * 65 + part * 16 + i];
                float mx = vv[0];
#pragma unroll
                for (int i = 1; i < 16; i++) mx = fmaxf(mx, vv[i]);
                mx = fmaxf(mx, __shfl_xor(mx, 1));
                mx = fmaxf(mx, __shfl_xor(mx, 2));
                float ssum = 0.f;
#pragma unroll
                for (int i = 0; i < 16; i++) { float e = __expf(vv[i] - mx); vv[i] = e; ssum += e; }
                ssum += __shfl_xor(ssum, 1);
                ssum += __shfl_xor(ssum, 2);
                float rs = 1.f / ssum;
                U8 o1, o2;
#pragma unroll
                for (int i = 0; i < 8; i++) o1.u[i] = f2bf(vv[i] * rs);
#pragma unroll
                for (int i = 0; i < 8; i++) o2.u[i] = f2bf(vv[8 + i] * rs);
                unsigned long long vb = ((unsigned long long)j * 1024 + lc * 128 + l2) * 64 + part * 16;
                *(short8*)&vws[vb] = o1.v;
                *(short8*)&vws[vb + 8] = o2.v;
            }
        }
    }

    // make this block's V stores visible to its own L1-cached reads
    __threadfence();

    // ---------------- epilogue: l2norm(U) -> M = Wout @ Un -> out = M @ V ----------
#pragma unroll
    for (int s = 0; s < 2; s++) {
        __syncthreads();
#pragma unroll
        for (int kn = 0; kn < 4; kn++)
#pragma unroll
            for (int r = 0; r < 4; r++)
                UF[(kn * 16 + lmod) * 133 + w * 16 + lquad * 4 + r] = uacc[s][kn][r];
        __syncthreads();
        if (t < 64) {
            const float* rp = &UF[t * 133];
            float ss = 0.f;
#pragma unroll 8
            for (int c = 0; c < 128; c++) ss += rp[c] * rp[c];
            UF[t * 133 + 128] = 1.f / (1e-6f + sqrtf(ss));
        }
        __syncthreads();
        {
            int kk = t >> 3, c0 = (t & 7) * 16;
            float rn = UF[kk * 133 + 128];
#pragma unroll
            for (int i = 0; i < 16; i++)
                UH[kk * 136 + c0 + i] = f2bf(UF[kk * 133 + c0 + i] * rn);
        }
        __syncthreads();
        v4f macc[4];
#pragma unroll
        for (int kn = 0; kn < 4; kn++) macc[kn] = (v4f){0.f, 0.f, 0.f, 0.f};
#pragma unroll
        for (int kc = 0; kc < 4; kc++) {
            short8 a = *(const short8*)&wof[(((s * 8 + w) * 4 + kc) * 64 + lane) * 8];
#pragma unroll
            for (int kn = 0; kn < 4; kn++) {
                short8 bb = *(const short8*)&UH[(kn * 16 + lmod) * 136 + kc * 32 + lquad * 8];
                macc[kn] = mfma16(a, bb, macc[kn]);
            }
        }
        __syncthreads();
#pragma unroll
        for (int kn = 0; kn < 4; kn++)
#pragma unroll
            for (int r = 0; r < 4; r++)
                MB[(w * 16 + lquad * 4 + r) * 72 + kn * 16 + lmod] = f2bf(macc[kn][r]);
        __syncthreads();
        // ---- out-GEMM for this s: out_tile = M @ V, operand-swapped MFMA ----
        // wave w owns o-tile w (channels w*16 + lmod); M B-frags straight from LDS
        short8 mfrag[2];
#pragma unroll
        for (int kc = 0; kc < 2; kc++)
            mfrag[kc] = *(const short8*)&MB[(w * 16 + lmod) * 72 + kc * 32 + lquad * 8];
        const long orow = (long)b * C_ * HW_ + (long)(i0 * 32) * W_ + i2 * 32
                        + (long)(w * 16 + lmod) * HW_ + (long)s * B_ * C_ * HW_;
#pragma unroll 4
        for (int ln = 0; ln < 64; ln++) {
            int l = ln * 16 + lmod;                               // V-frag row (A-operand)
            short8 b0  = *(const short8*)&vws[((unsigned long long)j * 1024 + l) * 64 + lquad * 8];
            short8 b1v = *(const short8*)&vws[((unsigned long long)j * 1024 + l) * 64 + 32 + lquad * 8];
            int lo = ln * 16 + lquad * 4;                         // first l of this lane's acc
            v4f acc = {0.f, 0.f, 0.f, 0.f};
            acc = mfma16(b0,  mfrag[0], acc);
            acc = mfma16(b1v, mfrag[1], acc);
            *(v4f*)&out[orow + (long)(lo >> 5) * W_ + (lo & 31)] = acc;
        }
    }
}

extern "C" void kernel_launch(void* const* d_in, const int* in_sizes, int n_in,
                              void* d_out, int out_size, void* d_ws, size_t ws_size,
                              hipStream_t stream) {
    (void)in_sizes; (void)n_in; (void)out_size; (void)ws_size;
    const float* x1    = (const float*)d_in[0];
    const float* x2    = (const float*)d_in[1];
    const float* w_v   = (const float*)d_in[2];
    const float* b_v   = (const float*)d_in[3];
    const float* w1_1  = (const float*)d_in[4];
    const float* b1_1  = (const float*)d_in[5];
    const float* w2_1  = (const float*)d_in[6];
    const float* b2_1  = (const float*)d_in[7];
    const float* wout1 = (const float*)d_in[8];
    const float* w1_2  = (const float*)d_in[9];
    const float* b1_2  = (const float*)d_in[10];
    const float* w2_2  = (const float*)d_in[11];
    const float* b2_2  = (const float*)d_in[12];
    const float* wout2 = (const float*)d_in[13];
    char* wsb  = (char*)d_ws;
    float* out = (float*)d_out;

    hipLaunchKernelGGL(prep_kernel, dim3(386), dim3(256), 0, stream,
                       w_v, b_v, w1_1, b1_1, w2_1, b2_1, wout1,
                       w1_2, b1_2, w2_2, b2_2, wout2, wsb);
    hipLaunchKernelGGL(fused_kernel, dim3(J_), dim3(512), 0, stream, x1, x2, wsb, out);
}